// Round 4
// baseline (4124.890 us; speedup 1.0000x reference)
//
#include <hip/hip_runtime.h>

#define DHN 512
#define TN  1024
#define BN  64
#define CH  16      // noise-staging chunk (steps)
#define KLO 256     // K in [0,KLO): MFMA waves; K in [KLO,512): VALU waves

typedef int int4v __attribute__((ext_vector_type(4)));

static __device__ __forceinline__ float sigm(float x) {
  return 1.0f / (1.0f + __expf(-x));
}

#if defined(__has_builtin)
#if __has_builtin(__builtin_amdgcn_sdot4)
#define HAVE_SDOT4 1
#endif
#endif

// All packed bytes are in [0,127]: signed == unsigned dot.
static __device__ __forceinline__ int dot4(int a, int b, int c) {
#ifdef HAVE_SDOT4
  return __builtin_amdgcn_sdot4(a, b, c, false);
#else
  c += (int)(signed char)(a)       * (int)(signed char)(b);
  c += (int)(signed char)(a >> 8)  * (int)(signed char)(b >> 8);
  c += (int)(signed char)(a >> 16) * (int)(signed char)(b >> 16);
  c += (int)(signed char)(a >> 24) * (int)(signed char)(b >> 24);
  return c;
#endif
}

// lgkm-only barrier: orders LDS producer->consumer handoffs WITHOUT draining
// vmcnt (noise-prefetch loads + xs stores stay in flight). sched_barrier(0)
// fences stop the compiler from hoisting LDS/MFMA ops across the asm.
static __device__ __forceinline__ void lds_barrier() {
  __builtin_amdgcn_sched_barrier(0);
  asm volatile("s_waitcnt lgkmcnt(0)\n\ts_barrier" ::: "memory");
  __builtin_amdgcn_sched_barrier(0);
}

// Wave64 sum via DPP (pure VALU). Result valid in lane 63 only.
#define DPPADD(x, ctrl)                                                    \
  do {                                                                     \
    int _m = __builtin_amdgcn_update_dpp(0, __builtin_bit_cast(int, (x)),  \
                                         (ctrl), 0xF, 0xF, true);          \
    (x) += __builtin_bit_cast(float, _m);                                  \
  } while (0)

static __device__ __forceinline__ float wave_sum_lane63(float x) {
  DPPADD(x, 0x111);  // row_shr:1
  DPPADD(x, 0x112);  // row_shr:2
  DPPADD(x, 0x114);  // row_shr:4
  DPPADD(x, 0x118);  // row_shr:8  -> lane 15 of each row has row sum
  DPPADD(x, 0x142);  // row_bcast:15
  DPPADD(x, 0x143);  // row_bcast:31 -> lane 63 has wave sum
  return x;
}

// Persistent RNN, one block per batch chain (64 blocks / 64 CUs).
// Round-4 change: ROLE-SPLIT waves so the MFMA pipe and the VALU pipe run in
// parallel (m114: an MFMA-issuing wave and a VALU-issuing wave on one SIMD
// co-schedule fully). Round-3 measured the all-MFMA matvec at 1305 MFMA-pipe
// cyc/SIMD/step (2 waves x 32 mfma x 20.4 cyc; MfmaUtil 41% busy-CU) with
// VALU+LDS+sync serializing on top -> 2517 cyc/step.
//   waves 0-3 (MFMA role, one per SIMD under round-robin wave->SIMD):
//     rows 128w..128w+127, K 0..255: 8 M-tiles x 4 q = 32 MFMA = 653 cyc.
//   waves 4-7 (VALU role): rows 128v..128v+127, K 256..511 via v_dot4:
//     1 ds_read_b32 + 64 readlane + 128 dot4 ~= 380-640 cyc VALU.
// Partials combine in LDS (psumA[h] + psumB[h]); i32 adds are exact, so x
// is bitwise identical to rounds 1-3 (same quantized bytes, same total).
// Costs a 2nd per-step lds_barrier (cross-wave partial visibility).
//
// mfma_i32_16x16x64_i8 layouts (A/B std CDNA; C/D HW-verified per m89):
//   A (16x64): row = lane&15,  k = 16*(lane>>4) + byte(0..15)
//   B (64x16): col = lane&15,  k = 16*(lane>>4) + byte(0..15)
//   D (16x16): col = lane&15,  row = 4*(lane>>4) + reg(0..3)
// B addr independent of lane&15 -> D replicated across cols; col 0 used.
__global__ __launch_bounds__(512, 2) void k_rnn(
    const float* __restrict__ u, const float* __restrict__ r0,
    const float* __restrict__ noise, const float* __restrict__ win,
    const float* __restrict__ taus, const float* __restrict__ wmat,
    const float* __restrict__ wout, const float* __restrict__ bias,
    float* __restrict__ xs, float* __restrict__ outp) {
  __shared__ float u_lds[TN];                        // 4 KB
  __shared__ float nz_lds[CH * DHN];                 // 32 KB
  __shared__ __align__(16) signed char rbuf[2][DHN]; // 1 KB, i8 r dbuf
  __shared__ float part_lds[8][CH];                  // out partials
  __shared__ __align__(16) int psumA[DHN];           // 2 KB, MFMA K-low dots
  __shared__ int psumB[DHN];                         // 2 KB, VALU K-high dots
  __shared__ float qs_lds[DHN];                      // 2 KB row quant scales

  const int h    = threadIdx.x;
  const int lane = h & 63;
  const int wv   = h >> 6;
  const int lrow = lane & 15;   // A-row within tile / D col
  const int lkg  = lane >> 4;   // k-group (16 bytes each)
  const int b    = blockIdx.x;
  const bool mrole = (wv < 4);
  const float* wrow = wmat + h * DHN;   // row h of _w

  // pass 1: row absmax of |_w[h,:]| (thread h owns row h's scale)
  float rmax = 1e-30f;
#pragma unroll 8
  for (int k = 0; k < 128; ++k) {
    float4 v = *(const float4*)(wrow + 4 * k);
    rmax = fmaxf(rmax, fabsf(v.x));
    rmax = fmaxf(rmax, fabsf(v.y));
    rmax = fmaxf(rmax, fabsf(v.z));
    rmax = fmaxf(rmax, fabsf(v.w));
  }
  const float qs = 127.0f / rmax;
  qs_lds[h] = qs;

  const float alpha  = 1.0f / taus[h];          // dt = 1
  const float beta   = 1.0f - alpha;
  const float win_h  = win[h];
  const float wout_h = wout[h];
  const float bias0  = bias[0];
  const float dscale = rmax * alpha * (1.0f / 16129.0f);  // rmax/127^2 * alpha
  float s = r0[b * DHN + h];                    // x_in at t=0 is RAW r0

  for (int i = h; i < TN; i += DHN) u_lds[i] = u[b * TN + i];
  rbuf[0][h] = (signed char)__float2int_rn(sigm(s) * 127.0f);  // r for t=0

  __syncthreads();  // qs_lds ready for fragment quantization

  // pass 2, role-specific weight staging. Quantization formula identical to
  // rounds 1-3 (|w| * qs_row, rn, clamp 0..127, LSB-first pack) -> identical
  // bytes -> identical integer dots.
  int4v wfrag[8][4];   // MFMA role: [m-tile][q] rows 128wv+16m+lrow
  int   wA[64], wB[64];  // VALU role: K-high dwords for rows rA, rB
  if (mrole) {
#pragma unroll
    for (int m = 0; m < 8; ++m) {
      const int row = 128 * wv + 16 * m + lrow;
      const float qsr = qs_lds[row];
      const float* rp = wmat + (size_t)row * DHN + lkg * 16;
#pragma unroll
      for (int q = 0; q < 4; ++q) {
        const float* cp = rp + q * 64;
        int4v wd;
#pragma unroll
        for (int d = 0; d < 4; ++d) {
          float4 v = *(const float4*)(cp + 4 * d);
          int q0 = min(max(__float2int_rn(fabsf(v.x) * qsr), 0), 127);
          int q1 = min(max(__float2int_rn(fabsf(v.y) * qsr), 0), 127);
          int q2 = min(max(__float2int_rn(fabsf(v.z) * qsr), 0), 127);
          int q3 = min(max(__float2int_rn(fabsf(v.w) * qsr), 0), 127);
          wd[d] = q0 | (q1 << 8) | (q2 << 16) | (q3 << 24);
        }
        wfrag[m][q] = wd;
      }
    }
  } else {
    const int vw = wv - 4;
    const int rA = 128 * vw + lane;
    const int rB = rA + 64;
    const float qsA = qs_lds[rA], qsB = qs_lds[rB];
    const float* pA = wmat + (size_t)rA * DHN + KLO;
    const float* pB = wmat + (size_t)rB * DHN + KLO;
#pragma unroll
    for (int j = 0; j < 64; ++j) {
      float4 va = *(const float4*)(pA + 4 * j);
      float4 vb = *(const float4*)(pB + 4 * j);
      int a0 = min(max(__float2int_rn(fabsf(va.x) * qsA), 0), 127);
      int a1 = min(max(__float2int_rn(fabsf(va.y) * qsA), 0), 127);
      int a2 = min(max(__float2int_rn(fabsf(va.z) * qsA), 0), 127);
      int a3 = min(max(__float2int_rn(fabsf(va.w) * qsA), 0), 127);
      wA[j] = a0 | (a1 << 8) | (a2 << 16) | (a3 << 24);
      int b0 = min(max(__float2int_rn(fabsf(vb.x) * qsB), 0), 127);
      int b1 = min(max(__float2int_rn(fabsf(vb.y) * qsB), 0), 127);
      int b2 = min(max(__float2int_rn(fabsf(vb.z) * qsB), 0), 127);
      int b3 = min(max(__float2int_rn(fabsf(vb.w) * qsB), 0), 127);
      wB[j] = b0 | (b1 << 8) | (b2 << 16) | (b3 << 24);
    }
  }

  const float* np = noise + (size_t)b * DHN + h;          // noise[t][b][h]
  float* xrow = xs + ((size_t)b * DHN + h) * TN;          // xs[b][h][t]

  // prefetch chunk 0 noise into regs
  float nreg[CH];
#pragma unroll
  for (int k = 0; k < CH; ++k) nreg[k] = np[(size_t)k * (BN * DHN)];

#pragma unroll 1
  for (int tc = 0; tc < TN; tc += CH) {
    __syncthreads();  // prev chunk's nz_lds/part_lds consumed; drains the
                      // nreg prefetch (needed now)
    if (tc > 0 && h < CH) {  // drain previous chunk's output partials
      float o = bias0;
#pragma unroll
      for (int wq = 0; wq < 8; ++wq) o += part_lds[wq][h];
      outp[b * TN + (tc - CH) + h] = o;
    }
#pragma unroll
    for (int k = 0; k < CH; ++k) nz_lds[k * DHN + h] = nreg[k];
    __syncthreads();
    if (tc + CH < TN) {
#pragma unroll
      for (int k = 0; k < CH; ++k)        // next chunk's loads fly under
        nreg[k] = np[(size_t)(tc + CH + k) * (BN * DHN)];  // compute
    }

#pragma unroll 1
    for (int t8 = 0; t8 < CH; t8 += 8) {
      // hoist chunk-static LDS reads out of the barrier-serialized region
      float ua[8];
      *(float4*)&ua[0] = *(const float4*)&u_lds[tc + t8];
      *(float4*)&ua[4] = *(const float4*)&u_lds[tc + t8 + 4];
      float nzv[8];
#pragma unroll
      for (int e = 0; e < 8; ++e) nzv[e] = nz_lds[(t8 + e) * DHN + h];

      float xv[8];
#pragma unroll
      for (int e = 0; e < 8; ++e) {
        // t = tc + t8 + e; tc,t8 even -> t&1 == e&1 (static LDS indexing)
        const signed char* rbp = &rbuf[e & 1][0];
        if (mrole) {
          // B fragments for K 0..255: addr = 64q + 16*lkg (broadcast per
          // 16-lane group, 4 distinct 16B lines) -> 4 ds_read_b128/wave.
          int4v bq[4];
#pragma unroll
          for (int q = 0; q < 4; ++q)
            bq[q] = *(const int4v*)(rbp + q * 64 + lkg * 16);
          const int4v zz = {0, 0, 0, 0};
          int4v acc[8];
#pragma unroll
          for (int m = 0; m < 8; ++m) acc[m] = zz;
#pragma unroll
          for (int q = 0; q < 4; ++q) {
#pragma unroll
            for (int m = 0; m < 8; ++m)
              acc[m] = __builtin_amdgcn_mfma_i32_16x16x64_i8(
                  wfrag[m][q], bq[q], acc[m], 0, 0, 0);
          }
          // col-0 lanes scatter D rows: dword 128wv+16m+4lkg+reg =
          // K-low dot of row 128wv+16m+4lkg+reg.
          if (lrow == 0) {
#pragma unroll
            for (int m = 0; m < 8; ++m)
              *(int4v*)&psumA[128 * wv + m * 16 + lkg * 4] = acc[m];
          }
        } else {
          // K-high r dwords: lane l holds dword 64+l (one b32/wave), then
          // readlane broadcast -> dot4 (SGPR src). 64 rl + 128 dot4.
          const int vw = wv - 4;
          const int rv = *(const int*)(rbp + KLO + 4 * lane);
          int accA = 0, accB = 0;
#pragma unroll
          for (int j = 0; j < 64; ++j) {
            const int rd = __builtin_amdgcn_readlane(rv, j);
            accA = dot4(wA[j], rd, accA);
            accB = dot4(wB[j], rd, accB);
          }
          psumB[128 * vw + lane]      = accA;
          psumB[128 * vw + 64 + lane] = accB;
        }
        lds_barrier();  // bar1: partials visible across waves
        const int dot = psumA[h] + psumB[h];   // exact i32 sum = full dot
        float x = beta * s + (float)dot * dscale
                + win_h * ua[e] + 0.1f * nzv[e];
        x = fminf(fmaxf(x, -40.0f), 40.0f);   // never binds on sane values
        xv[e] = x;
        float sp = sigm(x);                   // next x_in = sigmoid(x_new)
        rbuf[(e & 1) ^ 1][h] =
            (signed char)__float2int_rn(sigm(sp) * 127.0f);  // next r
        s = sp;
        // folded output projection: out[b,t] = bias + sum_h wout[h]*sp
        float po = wave_sum_lane63(wout_h * sp);
        if (lane == 63) part_lds[wv][t8 + e] = po;
        lds_barrier();  // bar2: rbuf(t+1) ready; psum reads done before
                        // next step's writes
      }
      float4 p0 = {xv[0], xv[1], xv[2], xv[3]};
      float4 p1 = {xv[4], xv[5], xv[6], xv[7]};
      *(float4*)(xrow + tc + t8)     = p0;    // 16B aligned
      *(float4*)(xrow + tc + t8 + 4) = p1;
    }
  }
  // drain last chunk's outputs
  __syncthreads();
  if (h < CH) {
    float o = bias0;
#pragma unroll
    for (int wq = 0; wq < 8; ++wq) o += part_lds[wq][h];
    outp[b * TN + (TN - CH) + h] = o;
  }
}

extern "C" void kernel_launch(void* const* d_in, const int* in_sizes, int n_in,
                              void* d_out, int out_size, void* d_ws, size_t ws_size,
                              hipStream_t stream) {
  const float* u     = (const float*)d_in[0];   // (64,1024,1) fp32
  const float* r0    = (const float*)d_in[1];   // (64,512,1)  fp32
  const float* noise = (const float*)d_in[2];   // (1024,64,512,1) fp32
  const float* win   = (const float*)d_in[3];   // (512,1) fp32
  // d_in[4] = m: diag +-1, cancelled by abs() -> unused
  const float* wout  = (const float*)d_in[5];   // (1,512) fp32
  const float* w_    = (const float*)d_in[6];   // (512,512) fp32
  const float* taus  = (const float*)d_in[7];   // (512,1) fp32
  const float* bias  = (const float*)d_in[8];   // (1,1) fp32

  float* outp = (float*)d_out;              // outputs (64,1024,1) fp32
  float* xs   = outp + BN * TN;             // xs_out (64,512,1024) fp32

  k_rnn<<<BN, DHN, 0, stream>>>(u, r0, noise, win, taus, w_, wout, bias,
                                xs, outp);
}

// Round 6
// 1439.938 us; speedup vs baseline: 2.8646x; 2.8646x over previous
//
#include <hip/hip_runtime.h>

#define DHN 512
#define TN  1024
#define BN  64
#define CH  16      // noise-staging chunk (steps)
#define KLO 320     // K in [0,KLO): MFMA (5 q-tiles); K in [KLO,512): dot4
#define NQ  5       // KLO / 64
#define NJ  48      // (512 - KLO) / 4 dwords per row for the dot4 part

typedef int int4v __attribute__((ext_vector_type(4)));

static __device__ __forceinline__ float sigm(float x) {
  return 1.0f / (1.0f + __expf(-x));
}

#if defined(__has_builtin)
#if __has_builtin(__builtin_amdgcn_sdot4)
#define HAVE_SDOT4 1
#endif
#endif

// All packed bytes are in [0,127]: signed == unsigned dot.
static __device__ __forceinline__ int dot4(int a, int b, int c) {
#ifdef HAVE_SDOT4
  return __builtin_amdgcn_sdot4(a, b, c, false);
#else
  c += (int)(signed char)(a)       * (int)(signed char)(b);
  c += (int)(signed char)(a >> 8)  * (int)(signed char)(b >> 8);
  c += (int)(signed char)(a >> 16) * (int)(signed char)(b >> 16);
  c += (int)(signed char)(a >> 24) * (int)(signed char)(b >> 24);
  return c;
#endif
}

// lgkm-only barrier: orders the rbuf/psum LDS handoffs WITHOUT draining vmcnt
// (noise-prefetch loads + xs stores stay in flight).
static __device__ __forceinline__ void lds_barrier() {
  __builtin_amdgcn_sched_barrier(0);
  asm volatile("s_waitcnt lgkmcnt(0)\n\ts_barrier" ::: "memory");
  __builtin_amdgcn_sched_barrier(0);
}

// Wave64 sum via DPP (pure VALU). Result valid in lane 63 only.
#define DPPADD(x, ctrl)                                                    \
  do {                                                                     \
    int _m = __builtin_amdgcn_update_dpp(0, __builtin_bit_cast(int, (x)),  \
                                         (ctrl), 0xF, 0xF, true);          \
    (x) += __builtin_bit_cast(float, _m);                                  \
  } while (0)

static __device__ __forceinline__ float wave_sum_lane63(float x) {
  DPPADD(x, 0x111);  // row_shr:1
  DPPADD(x, 0x112);  // row_shr:2
  DPPADD(x, 0x114);  // row_shr:4
  DPPADD(x, 0x118);  // row_shr:8  -> lane 15 of each row has row sum
  DPPADD(x, 0x142);  // row_bcast:15
  DPPADD(x, 0x143);  // row_bcast:31 -> lane 63 has wave sum
  return x;
}

// Persistent RNN, one block per batch chain (64 blocks / 64 CUs).
// Round-5 (resubmitted round-6: previous bench died to a container fault,
// not a kernel error): SYMMETRIC per-wave K-split across MFMA + VALU pipes.
// Round 4's role-split spilled: VALU-role weights (128 dwords, must be VGPR
// for v_dot4) + MFMA-role frags (128 dwords) were both live -> scratch
// (WRITE_SIZE +180MB, 4x regression). Round 3 proved MFMA A-frags go to
// AGPRs (VGPR_Count=104 with 128 dwords of frags), so the fix: EVERY wave
// owns its 64 rows and computes K[0,320) via MFMA (20 frags -> AGPR) and
// K[320,512) via dot4 (48 dwords -> VGPR). Uniform allocation, no divergent
// live ranges. For this N=1 matvec the useful rates are ~equal (MFMA ~50
// MAC/cyc/SIMD after 16x column waste, dot4 ~57), so the split ~halves the
// round-3 matvec time: MFMA pipe 40x20.4=816 cyc/SIMD vs 1305.
// D-redistribution is within-wave (wave w's D rows are its own threads'
// rows): ds_write + lgkm + ds_read, no extra barrier -> 1 barrier/step.
// i32 partial adds are exact -> x bitwise identical to rounds 0-3.
//
// mfma_i32_16x16x64_i8 layouts (A/B std CDNA; C/D HW-verified per m89):
//   A (16x64): row = lane&15,  k = 16*(lane>>4) + byte(0..15)
//   B (64x16): col = lane&15,  k = 16*(lane>>4) + byte(0..15)
//   D (16x16): col = lane&15,  row = 4*(lane>>4) + reg(0..3)
// B addr independent of lane&15 -> D replicated across cols; col 0 used.
__global__ __launch_bounds__(512, 2) void k_rnn(
    const float* __restrict__ u, const float* __restrict__ r0,
    const float* __restrict__ noise, const float* __restrict__ win,
    const float* __restrict__ taus, const float* __restrict__ wmat,
    const float* __restrict__ wout, const float* __restrict__ bias,
    float* __restrict__ xs, float* __restrict__ outp) {
  __shared__ float u_lds[TN];                        // 4 KB
  __shared__ float nz_lds[CH * DHN];                 // 32 KB
  // inner dim padded to 576 so the per-lane K-high dword read
  // (offset KLO + 4*lane, up to byte 575) stays inside the row; lanes
  // >= NJ read pad bytes but their values are never consumed (readlane
  // only sources lanes j < NJ).
  __shared__ __align__(16) signed char rbuf[2][576];
  __shared__ float part_lds[8][CH];                  // out partials
  __shared__ __align__(16) int psum[DHN];            // 2 KB, MFMA K-low dots
  __shared__ float qs_lds[DHN];                      // 2 KB row quant scales

  const int h    = threadIdx.x;
  const int lane = h & 63;
  const int wv   = h >> 6;
  const int lrow = lane & 15;   // A-row within tile / D col
  const int lkg  = lane >> 4;   // k-group (16 bytes each)
  const int b    = blockIdx.x;
  const float* wrow = wmat + h * DHN;   // row h of _w

  // pass 1: row absmax of |_w[h,:]| (thread h owns row h's scale)
  float rmax = 1e-30f;
#pragma unroll 8
  for (int k = 0; k < 128; ++k) {
    float4 v = *(const float4*)(wrow + 4 * k);
    rmax = fmaxf(rmax, fabsf(v.x));
    rmax = fmaxf(rmax, fabsf(v.y));
    rmax = fmaxf(rmax, fabsf(v.z));
    rmax = fmaxf(rmax, fabsf(v.w));
  }
  const float qs = 127.0f / rmax;
  qs_lds[h] = qs;

  const float alpha  = 1.0f / taus[h];          // dt = 1
  const float beta   = 1.0f - alpha;
  const float win_h  = win[h];
  const float wout_h = wout[h];
  const float bias0  = bias[0];
  const float dscale = rmax * alpha * (1.0f / 16129.0f);  // rmax/127^2 * alpha
  float s = r0[b * DHN + h];                    // x_in at t=0 is RAW r0

  for (int i = h; i < TN; i += DHN) u_lds[i] = u[b * TN + i];
  rbuf[0][h] = (signed char)__float2int_rn(sigm(s) * 127.0f);  // r for t=0

  __syncthreads();  // qs_lds ready for fragment quantization

  // pass 2a: dot4 weights for OWN row h, K-high [KLO,512): 48 dwords (VGPR).
  // Quantization formula identical to all prior rounds (|w|*qs_row, rn,
  // clamp 0..127, LSB-first pack) -> identical bytes -> identical i32 dots.
  int wd[NJ];
  {
    const float* ph = wrow + KLO;
#pragma unroll
    for (int j = 0; j < NJ; ++j) {
      float4 v = *(const float4*)(ph + 4 * j);
      int q0 = min(max(__float2int_rn(fabsf(v.x) * qs), 0), 127);
      int q1 = min(max(__float2int_rn(fabsf(v.y) * qs), 0), 127);
      int q2 = min(max(__float2int_rn(fabsf(v.z) * qs), 0), 127);
      int q3 = min(max(__float2int_rn(fabsf(v.w) * qs), 0), 127);
      wd[j] = q0 | (q1 << 8) | (q2 << 16) | (q3 << 24);
    }
  }

  // pass 2b: MFMA A-frags for the wave's 64 rows, K-low [0,KLO).
  // wfrag[m][q]: lane holds W[64wv + 16m + lrow][64q + 16lkg .. +15] as i8.
  // Consumed only by MFMA -> compiler places in AGPRs (round-3 evidence).
  int4v wfrag[4][NQ];
#pragma unroll
  for (int m = 0; m < 4; ++m) {
    const int row = 64 * wv + 16 * m + lrow;
    const float qsr = qs_lds[row];
    const float* rp = wmat + (size_t)row * DHN + lkg * 16;
#pragma unroll
    for (int q = 0; q < NQ; ++q) {
      const float* cp = rp + q * 64;
      int4v wq;
#pragma unroll
      for (int d = 0; d < 4; ++d) {
        float4 v = *(const float4*)(cp + 4 * d);
        int q0 = min(max(__float2int_rn(fabsf(v.x) * qsr), 0), 127);
        int q1 = min(max(__float2int_rn(fabsf(v.y) * qsr), 0), 127);
        int q2 = min(max(__float2int_rn(fabsf(v.z) * qsr), 0), 127);
        int q3 = min(max(__float2int_rn(fabsf(v.w) * qsr), 0), 127);
        wq[d] = q0 | (q1 << 8) | (q2 << 16) | (q3 << 24);
      }
      wfrag[m][q] = wq;
    }
  }

  const float* np = noise + (size_t)b * DHN + h;          // noise[t][b][h]
  float* xrow = xs + ((size_t)b * DHN + h) * TN;          // xs[b][h][t]

  // prefetch chunk 0 noise into regs
  float nreg[CH];
#pragma unroll
  for (int k = 0; k < CH; ++k) nreg[k] = np[(size_t)k * (BN * DHN)];

#pragma unroll 1
  for (int tc = 0; tc < TN; tc += CH) {
    __syncthreads();  // prev chunk's nz_lds/part_lds consumed; drains the
                      // nreg prefetch (needed now)
    if (tc > 0 && h < CH) {  // drain previous chunk's output partials
      float o = bias0;
#pragma unroll
      for (int wq = 0; wq < 8; ++wq) o += part_lds[wq][h];
      outp[b * TN + (tc - CH) + h] = o;
    }
#pragma unroll
    for (int k = 0; k < CH; ++k) nz_lds[k * DHN + h] = nreg[k];
    __syncthreads();
    if (tc + CH < TN) {
#pragma unroll
      for (int k = 0; k < CH; ++k)        // next chunk's loads fly under
        nreg[k] = np[(size_t)(tc + CH + k) * (BN * DHN)];  // compute
    }

#pragma unroll 1
    for (int t8 = 0; t8 < CH; t8 += 8) {
      // hoist chunk-static LDS reads out of the barrier-serialized region
      float ua[8];
      *(float4*)&ua[0] = *(const float4*)&u_lds[tc + t8];
      *(float4*)&ua[4] = *(const float4*)&u_lds[tc + t8 + 4];
      float nzv[8];
#pragma unroll
      for (int e = 0; e < 8; ++e) nzv[e] = nz_lds[(t8 + e) * DHN + h];

      float xv[8];
#pragma unroll
      for (int e = 0; e < 8; ++e) {
        // t = tc + t8 + e; tc,t8 even -> t&1 == e&1 (static LDS indexing)
        const signed char* rbp = &rbuf[e & 1][0];

        // --- K-low via MFMA ---
        // B fragments: addr = 64q + 16*lkg (broadcast per 16-lane group,
        // 4 distinct 16B lines) -> NQ ds_read_b128 per wave.
        int4v bq[NQ];
#pragma unroll
        for (int q = 0; q < NQ; ++q)
          bq[q] = *(const int4v*)(rbp + q * 64 + lkg * 16);
        const int4v zz = {0, 0, 0, 0};
        int4v acc[4];
#pragma unroll
        for (int m = 0; m < 4; ++m) acc[m] = zz;
#pragma unroll
        for (int q = 0; q < NQ; ++q) {
#pragma unroll
          for (int m = 0; m < 4; ++m)
            acc[m] = __builtin_amdgcn_mfma_i32_16x16x64_i8(
                wfrag[m][q], bq[q], acc[m], 0, 0, 0);
        }
        // within-wave redistribution: col-0 lanes (0,16,32,48) scatter
        // D rows -> psum[64wv + 16m + 4lkg + reg]; thread h then reads
        // psum[h] (same wave: ds_write -> lgkm wait -> ds_read, no barrier;
        // psum regions are wave-private so no cross-wave race either).
        if (lrow == 0) {
#pragma unroll
          for (int m = 0; m < 4; ++m)
            *(int4v*)&psum[64 * wv + m * 16 + lkg * 4] = acc[m];
        }

        // --- K-high via dot4 (overlaps the MFMA pipe) ---
        // lane l holds r dword KLO/4 + l (only l < NJ consumed); readlane
        // -> SGPR feeds v_dot4 directly.
        const int rv = *(const int*)(rbp + KLO + 4 * lane);
        int accL = 0;
#pragma unroll
        for (int j = 0; j < NJ; ++j) {
          const int rd = __builtin_amdgcn_readlane(rv, j);
          accL = dot4(wd[j], rd, accL);
        }

        const int dot = psum[h] + accL;   // exact i32 sum = full-K dot
        float x = beta * s + (float)dot * dscale
                + win_h * ua[e] + 0.1f * nzv[e];
        x = fminf(fmaxf(x, -40.0f), 40.0f);   // never binds on sane values
        xv[e] = x;
        float sp = sigm(x);                   // next x_in = sigmoid(x_new)
        rbuf[(e & 1) ^ 1][h] =
            (signed char)__float2int_rn(sigm(sp) * 127.0f);  // next r
        s = sp;
        // folded output projection: out[b,t] = bias + sum_h wout[h]*sp
        float po = wave_sum_lane63(wout_h * sp);
        if (lane == 63) part_lds[wv][t8 + e] = po;
        lds_barrier();  // rbuf(t+1) ready; lgkm-only, no vmcnt drain
      }
      float4 p0 = {xv[0], xv[1], xv[2], xv[3]};
      float4 p1 = {xv[4], xv[5], xv[6], xv[7]};
      *(float4*)(xrow + tc + t8)     = p0;    // 16B aligned
      *(float4*)(xrow + tc + t8 + 4) = p1;
    }
  }
  // drain last chunk's outputs
  __syncthreads();
  if (h < CH) {
    float o = bias0;
#pragma unroll
    for (int wq = 0; wq < 8; ++wq) o += part_lds[wq][h];
    outp[b * TN + (TN - CH) + h] = o;
  }
}

extern "C" void kernel_launch(void* const* d_in, const int* in_sizes, int n_in,
                              void* d_out, int out_size, void* d_ws, size_t ws_size,
                              hipStream_t stream) {
  const float* u     = (const float*)d_in[0];   // (64,1024,1) fp32
  const float* r0    = (const float*)d_in[1];   // (64,512,1)  fp32
  const float* noise = (const float*)d_in[2];   // (1024,64,512,1) fp32
  const float* win   = (const float*)d_in[3];   // (512,1) fp32
  // d_in[4] = m: diag +-1, cancelled by abs() -> unused
  const float* wout  = (const float*)d_in[5];   // (1,512) fp32
  const float* w_    = (const float*)d_in[6];   // (512,512) fp32
  const float* taus  = (const float*)d_in[7];   // (512,1) fp32
  const float* bias  = (const float*)d_in[8];   // (1,1) fp32

  float* outp = (float*)d_out;              // outputs (64,1024,1) fp32
  float* xs   = outp + BN * TN;             // xs_out (64,512,1024) fp32

  k_rnn<<<BN, DHN, 0, stream>>>(u, r0, noise, win, taus, w_, wout, bias,
                                xs, outp);
}